// Round 9
// baseline (239.931 us; speedup 1.0000x reference)
//
#include <hip/hip_runtime.h>

// Rank2SymmetricTensorHead — prep(bucket||stats||W1-fold) + main(edges + G-GEMM).
// Algebra (absmax 0.0 since round 3): layernorm is affine per edge =>
//   z[u,k] = sum_l S1[u,l]*G[l,k] - S2[u]*wbar[k] + S3[u]*bbar[k] + b1[k]
// with G[l,k] = sum_c emb[n,l,c]*W1p[c,k],  W1p = lw ⊙ W1 (row-scaled),
// wbar = col-sums of W1p, bbar = col-sums of lb ⊙ W1.
// S1[6][9],S2[6],S3[6] per node from edges; per-edge mu/var from per-node
// mbar[9]+Gram[45]. Inner GEMM loop uses NO LDS: emb rows are wave-uniform
// (SMEM s_load), W1p is coalesced float2 (VMEM), acc in VGPRs.

#define SQ3  1.73205080756887729f
#define SQ15 3.87298334620741688f
#define SQ5  2.23606797749978970f

__device__ __forceinline__ float dpp_sum64(float v) {
    // 64-lane sum, result valid in lane 63. Pure VALU.
    int x;
    x = __builtin_amdgcn_update_dpp(0, __float_as_int(v), 0x111, 0xF, 0xF, true); v += __int_as_float(x);
    x = __builtin_amdgcn_update_dpp(0, __float_as_int(v), 0x112, 0xF, 0xF, true); v += __int_as_float(x);
    x = __builtin_amdgcn_update_dpp(0, __float_as_int(v), 0x114, 0xF, 0xF, true); v += __int_as_float(x);
    x = __builtin_amdgcn_update_dpp(0, __float_as_int(v), 0x118, 0xF, 0xF, true); v += __int_as_float(x);
    x = __builtin_amdgcn_update_dpp(0, __float_as_int(v), 0x142, 0xA, 0xF, true); v += __int_as_float(x);
    x = __builtin_amdgcn_update_dpp(0, __float_as_int(v), 0x143, 0xC, 0xF, true); v += __int_as_float(x);
    return v;
}

__device__ __forceinline__ void wave_fence() {
    __builtin_amdgcn_wave_barrier();
    asm volatile("" ::: "memory");
}

// blocks [0,PB): edge bucketing + batch counts
// blocks [PB,PB+SB): per-node stats (mbar[9]+Gram[45]), 1 wave/node, no LDS
// block  PB+SB: W1 fold (W1p, wbar, bbar)
__global__ __launch_bounds__(256)
void prep_kernel(const int* __restrict__ idx1, const int* __restrict__ batch,
                 int* __restrict__ cnt, int* __restrict__ bcnt, int* __restrict__ elist,
                 const float* __restrict__ emb, float* __restrict__ stats,
                 const float* __restrict__ ln_w, const float* __restrict__ ln_b,
                 const float* __restrict__ W1, float* __restrict__ W1p,
                 float* __restrict__ wbar, float* __restrict__ bbar,
                 int slot, int E, int N, int PB, int SB)
{
    const int b = blockIdx.x;
    if (b < PB) {
        const int i  = b * 256 + threadIdx.x;
        const int i4 = i * 4;
        if (i4 + 3 < E) {
            const int4 v = *(const int4*)&idx1[i4];
            int p;
            p = atomicAdd(&cnt[v.x], 1); if (p < slot) elist[(size_t)v.x * slot + p] = i4;
            p = atomicAdd(&cnt[v.y], 1); if (p < slot) elist[(size_t)v.y * slot + p] = i4 + 1;
            p = atomicAdd(&cnt[v.z], 1); if (p < slot) elist[(size_t)v.z * slot + p] = i4 + 2;
            p = atomicAdd(&cnt[v.w], 1); if (p < slot) elist[(size_t)v.w * slot + p] = i4 + 3;
        } else {
            for (int k2 = i4; k2 < E; ++k2) {
                const int nn = idx1[k2];
                const int p = atomicAdd(&cnt[nn], 1);
                if (p < slot) elist[(size_t)nn * slot + p] = k2;
            }
        }
        if (i < N) atomicAdd(&bcnt[batch[i]], 1);
        return;
    }
    if (b < PB + SB) {
        const int lane = threadIdx.x & 63;
        const int n = (b - PB) * 4 + (threadIdx.x >> 6);
        if (n >= N) return;
        const float* eb = emb + (size_t)n * 1152;
        float er0[9], er1[9];
        #pragma unroll
        for (int l = 0; l < 9; ++l) { er0[l] = eb[l * 128 + lane]; er1[l] = eb[l * 128 + 64 + lane]; }
        float* st = stats + (size_t)n * 56;
        #pragma unroll
        for (int l = 0; l < 9; ++l) {
            const float tot = dpp_sum64(er0[l] + er1[l]);
            if (lane == 63) st[l] = tot;
        }
        int idx = 9;
        #pragma unroll
        for (int l = 0; l < 9; ++l) {
            #pragma unroll
            for (int l2 = l; l2 < 9; ++l2) {
                const float tot = dpp_sum64(er0[l] * er0[l2] + er1[l] * er1[l2]);
                if (lane == 63) st[idx] = tot;
                ++idx;
            }
        }
        return;
    }
    // ---- W1 fold: one block, 256 threads = (k 0..127) x (c-half) ----
    {
        __shared__ float red[2][128][2];
        const int k = threadIdx.x & 127, hf = threadIdx.x >> 7;
        float wb = 0.f, bbv = 0.f;
        const int c0 = hf * 64;
        for (int c = c0; c < c0 + 64; ++c) {
            const float w  = W1[c * 128 + k];
            const float wp = ln_w[c] * w;
            W1p[c * 128 + k] = wp;
            wb  += wp;
            bbv += ln_b[c] * w;
        }
        red[hf][k][0] = wb; red[hf][k][1] = bbv;
        __syncthreads();
        if (hf == 0) {
            wbar[k] = red[0][k][0] + red[1][k][0];
            bbar[k] = red[0][k][1] + red[1][k][1];
        }
    }
}

// main: 4 waves/block, each wave owns 2 nodes end-to-end.
__global__ __launch_bounds__(256)
void main_kernel(const float* __restrict__ emb, const float* __restrict__ vec,
                 const int* __restrict__ cnt, const int* __restrict__ elist, int slot,
                 const float* __restrict__ sph_w, const float* __restrict__ stats,
                 const float* __restrict__ W1p, const float* __restrict__ wbar,
                 const float* __restrict__ bbar, const float* __restrict__ b1,
                 const float* __restrict__ W2, const float* __restrict__ b2,
                 const int* __restrict__ batch, const int* __restrict__ bcnt,
                 float* __restrict__ out, int N)
{
    __shared__ float S_sh[4][2][68];   // per-wave, per-node: S1[54],S2[6],S3[6]

    const int lane = threadIdx.x & 63;
    const int wv   = threadIdx.x >> 6;
    const int n0   = (blockIdx.x * 4 + wv) * 2;
    if (n0 >= N) return;

    // ============ phase 1: edges -> S_sh (wave-local, DPP) ============
    const float spw0 = sph_w[0], spw1 = sph_w[1], spw2 = sph_w[2];
    #pragma unroll
    for (int s = 0; s < 2; ++s) {
        const int n = n0 + s;
        if (n >= N) break;
        const int   cntn = cnt[n];
        const int   cnE  = min(cntn, slot);
        const float invc = 1.f / (float)(cntn > 0 ? cntn : 1);
        const float inv128 = 1.f / 128.f;
        const float* st = stats + (size_t)n * 56;   // wave-uniform

        float t1[9], mru = 0.f, op[6];
        #pragma unroll
        for (int l = 0; l < 9; ++l) t1[l] = 0.f;
        #pragma unroll
        for (int u = 0; u < 6; ++u) op[u] = 0.f;

        if (lane < cnE) {
            const int e = elist[(size_t)n * slot + lane];
            const float vx = vec[e * 3 + 0];
            const float vy = vec[e * 3 + 1];
            const float vz = vec[e * 3 + 2];
            const float rr = vx * vx + vy * vy + vz * vz;

            const float a1x = SQ3 * vx, a1y = SQ3 * vy, a1z = SQ3 * vz;
            const float q0 = SQ15 * vx * vy;
            const float q1 = SQ15 * vy * vz;
            const float q2 = 0.5f * SQ5 * (3.f * vz * vz - rr);
            const float q3 = SQ15 * vx * vz;
            const float q4 = 0.5f * SQ15 * (vx * vx - vy * vy);
            const float inv1 = spw1 * rsqrtf((a1x*a1x + a1y*a1y + a1z*a1z) * (1.f/3.f) + 1e-6f);
            const float inv2 = spw2 * rsqrtf((q0*q0 + q1*q1 + q2*q2 + q3*q3 + q4*q4) * (1.f/5.f) + 1e-6f);

            float sh[9];
            sh[0] = spw0 * rsqrtf(1.0f + 1e-6f);
            sh[1] = a1x * inv1; sh[2] = a1y * inv1; sh[3] = a1z * inv1;
            sh[4] = q0 * inv2;  sh[5] = q1 * inv2;  sh[6] = q2 * inv2;
            sh[7] = q3 * inv2;  sh[8] = q4 * inv2;

            float mu = 0.f;
            #pragma unroll
            for (int l = 0; l < 9; ++l) mu += sh[l] * st[l];
            mu *= inv128;

            float x2 = 0.f;
            {
                int idx = 9;
                #pragma unroll
                for (int l = 0; l < 9; ++l) {
                    x2 += st[idx] * sh[l] * sh[l]; ++idx;
                    #pragma unroll
                    for (int l2 = l + 1; l2 < 9; ++l2) {
                        x2 += st[idx] * (2.f * sh[l] * sh[l2]); ++idx;
                    }
                }
            }
            x2 *= inv128;

            const float rinv = rsqrtf(x2 - mu * mu + 1e-5f);
            #pragma unroll
            for (int l = 0; l < 9; ++l) t1[l] = rinv * sh[l];
            mru = rinv * mu;
            op[0] = vx*vx; op[1] = vx*vy; op[2] = vx*vz;
            op[3] = vy*vy; op[4] = vy*vz; op[5] = vz*vz;
        }

        #pragma unroll
        for (int u = 0; u < 6; ++u) {
            #pragma unroll
            for (int l = 0; l < 9; ++l) {
                const float tot = dpp_sum64(op[u] * t1[l]);
                if (lane == 63) S_sh[wv][s][u * 9 + l] = tot * invc;
            }
        }
        #pragma unroll
        for (int u = 0; u < 6; ++u) {
            const float tot = dpp_sum64(op[u] * mru);
            if (lane == 63) S_sh[wv][s][54 + u] = tot * invc;
        }
        #pragma unroll
        for (int u = 0; u < 6; ++u) {
            const float tot = dpp_sum64(op[u]);
            if (lane == 63) S_sh[wv][s][60 + u] = tot * invc;
        }
    }
    wave_fence();

    // ============ phase 2: G = emb_n (9x128) x W1p (128x128), 2 nodes ======
    // lane owns k2=2*lane. emb rows are wave-uniform -> SMEM; W1p -> VMEM.
    const int k2 = 2 * lane;
    const size_t n1c = (size_t)((n0 + 1 < N) ? n0 + 1 : n0);
    const float* eb0 = emb + (size_t)n0 * 1152;
    const float* eb1 = emb + n1c * 1152;

    float2 g0[9], g1[9];
    #pragma unroll
    for (int l = 0; l < 9; ++l) { g0[l] = make_float2(0.f, 0.f); g1[l] = make_float2(0.f, 0.f); }

    const float* wp = W1p + k2;
    for (int c0 = 0; c0 < 128; c0 += 8) {
        float2 w8[8];
        #pragma unroll
        for (int cc = 0; cc < 8; ++cc)
            w8[cc] = *(const float2*)(wp + (size_t)(c0 + cc) * 128);
        #pragma unroll
        for (int l = 0; l < 9; ++l) {
            const float* r = eb0 + l * 128 + c0;   // uniform -> s_load
            #pragma unroll
            for (int cc = 0; cc < 8; ++cc) {
                const float e = r[cc];
                g0[l].x = fmaf(e, w8[cc].x, g0[l].x);
                g0[l].y = fmaf(e, w8[cc].y, g0[l].y);
            }
        }
        #pragma unroll
        for (int l = 0; l < 9; ++l) {
            const float* r = eb1 + l * 128 + c0;
            #pragma unroll
            for (int cc = 0; cc < 8; ++cc) {
                const float e = r[cc];
                g1[l].x = fmaf(e, w8[cc].x, g1[l].x);
                g1[l].y = fmaf(e, w8[cc].y, g1[l].y);
            }
        }
    }

    // ============ phase 3: z = S1*G - S2*wbar + S3*bbar + b1; silu; W2 ======
    const float2 wbv = *(const float2*)(wbar + k2);
    const float2 bbv = *(const float2*)(bbar + k2);
    const float2 b1v = *(const float2*)(b1 + k2);
    const float2 w2v = *(const float2*)(W2 + k2);

    #pragma unroll
    for (int s = 0; s < 2; ++s) {
        const int n = n0 + s;
        if (n >= N) break;
        const float* Sp = &S_sh[wv][s][0];
        float sv[6];
        #pragma unroll
        for (int u = 0; u < 6; ++u) {
            float zx = b1v.x, zy = b1v.y;
            #pragma unroll
            for (int l = 0; l < 9; ++l) {
                const float s1 = Sp[u * 9 + l];
                const float2 g = (s == 0) ? g0[l] : g1[l];
                zx = fmaf(s1, g.x, zx);
                zy = fmaf(s1, g.y, zy);
            }
            const float S2u = Sp[54 + u], S3u = Sp[60 + u];
            zx = fmaf(-S2u, wbv.x, fmaf(S3u, bbv.x, zx));
            zy = fmaf(-S2u, wbv.y, fmaf(S3u, bbv.y, zy));
            const float gx = zx / (1.f + __expf(-zx));
            const float gy = zy / (1.f + __expf(-zy));
            sv[u] = dpp_sum64(fmaf(gx, w2v.x, gy * w2v.y));
        }
        if (lane == 63) {
            const float bb2 = b2[0];
            const int bidx = batch[n];
            const int cb = bcnt[bidx];
            const float ic = 1.f / (float)(cb > 0 ? cb : 1);
            const int base = bidx * 9;
            const float o0 = (sv[0] + bb2) * ic;
            const float o1 = (sv[1] + bb2) * ic;
            const float o2 = (sv[2] + bb2) * ic;
            const float o3 = (sv[3] + bb2) * ic;
            const float o4 = (sv[4] + bb2) * ic;
            const float o5 = (sv[5] + bb2) * ic;
            atomicAdd(&out[base + 0], o0);
            atomicAdd(&out[base + 1], o1);
            atomicAdd(&out[base + 2], o2);
            atomicAdd(&out[base + 3], o1);
            atomicAdd(&out[base + 4], o3);
            atomicAdd(&out[base + 5], o4);
            atomicAdd(&out[base + 6], o2);
            atomicAdd(&out[base + 7], o4);
            atomicAdd(&out[base + 8], o5);
        }
    }
}

extern "C" void kernel_launch(void* const* d_in, const int* in_sizes, int n_in,
                              void* d_out, int out_size, void* d_ws, size_t ws_size,
                              hipStream_t stream) {
    const float* emb   = (const float*)d_in[0];
    const float* vec   = (const float*)d_in[1];
    const int*   eidx  = (const int*)  d_in[2];
    const int*   batch = (const int*)  d_in[3];
    const float* sph_w = (const float*)d_in[4];
    const float* ln_w  = (const float*)d_in[5];
    const float* ln_b  = (const float*)d_in[6];
    const float* W1    = (const float*)d_in[7];
    const float* b1    = (const float*)d_in[8];
    const float* W2    = (const float*)d_in[9];
    const float* b2    = (const float*)d_in[10];

    const int N = in_sizes[3];
    const int E = in_sizes[1] / 3;
    const int B = out_size / 9;
    const int* idx1 = eidx + E;   // edge_index[1]

    // ws: [cnt N][bcnt B][elist N*slot][stats N*56][W1p 16384][wbar 128][bbar 128]
    int slot = 64;
    {
        const size_t base = (size_t)(N + B) + (size_t)N * 56 + 16384 + 256;
        while (slot > 1 && (base + (size_t)N * slot) * 4 > ws_size) slot >>= 1;
    }
    int*   cnt   = (int*)d_ws;
    int*   bcnt  = cnt + N;
    int*   elist = bcnt + B;
    float* stats = (float*)(elist + (size_t)N * slot);
    float* W1p   = stats + (size_t)N * 56;
    float* wbar  = W1p + 16384;
    float* bbar  = wbar + 128;

    hipMemsetAsync(d_out, 0, (size_t)out_size * sizeof(float), stream);
    hipMemsetAsync(cnt, 0, (size_t)(N + B) * sizeof(int), stream);

    const int PB = (max((E + 3) / 4, N) + 255) / 256;
    const int SB = (N + 3) / 4;
    prep_kernel<<<PB + SB + 1, 256, 0, stream>>>(idx1, batch, cnt, bcnt, elist,
                                                 emb, stats, ln_w, ln_b, W1,
                                                 W1p, wbar, bbar, slot, E, N, PB, SB);
    main_kernel<<<(N + 7) / 8, 256, 0, stream>>>(
        emb, vec, cnt, elist, slot, sph_w, stats, W1p, wbar, bbar,
        b1, W2, b2, batch, bcnt, (float*)d_out, N);
}

// Round 10
// 189.274 us; speedup vs baseline: 1.2676x; 1.2676x over previous
//
#include <hip/hip_runtime.h>

// Rank2SymmetricTensorHead — prep(bucket||stats||W1-fold) + main(edges + G-GEMM).
// Algebra (absmax 0.0 since round 3): layernorm is affine per edge =>
//   z[u,k] = sum_l S1[u,l]*G[l,k] - S2[u]*wbar[k] + S3[u]*bbar[k] + b1[k]
// with G[l,k] = sum_c emb[n,l,c]*W1p[c,k],  W1p = lw ⊙ W1 (row-scaled),
// wbar = col-sums of W1p, bbar = col-sums of lb ⊙ W1.
// S1/S2/S3 per node from edges; per-edge mu/var from per-node mbar[9]+Gram[45].
// main: wave = 1 node; node index forced wave-uniform via readfirstlane so emb
// rows compile to s_load (SMEM pipe); W1p is coalesced float2 (VMEM); acc in
// VGPRs; inner loop has ZERO DS instructions. 2048 blocks, VGPR<=64.

#define SQ3  1.73205080756887729f
#define SQ15 3.87298334620741688f
#define SQ5  2.23606797749978970f

__device__ __forceinline__ float dpp_sum64(float v) {
    // 64-lane sum, result valid in lane 63. Pure VALU.
    int x;
    x = __builtin_amdgcn_update_dpp(0, __float_as_int(v), 0x111, 0xF, 0xF, true); v += __int_as_float(x);
    x = __builtin_amdgcn_update_dpp(0, __float_as_int(v), 0x112, 0xF, 0xF, true); v += __int_as_float(x);
    x = __builtin_amdgcn_update_dpp(0, __float_as_int(v), 0x114, 0xF, 0xF, true); v += __int_as_float(x);
    x = __builtin_amdgcn_update_dpp(0, __float_as_int(v), 0x118, 0xF, 0xF, true); v += __int_as_float(x);
    x = __builtin_amdgcn_update_dpp(0, __float_as_int(v), 0x142, 0xA, 0xF, true); v += __int_as_float(x);
    x = __builtin_amdgcn_update_dpp(0, __float_as_int(v), 0x143, 0xC, 0xF, true); v += __int_as_float(x);
    return v;
}

__device__ __forceinline__ void wave_fence() {
    __builtin_amdgcn_wave_barrier();
    asm volatile("" ::: "memory");
}

// blocks [0,PB): edge bucketing + batch counts
// blocks [PB,PB+SB): per-node stats (mbar[9]+Gram[45]), 1 wave/node, no LDS
// block  PB+SB: W1 fold (W1p, wbar, bbar)
__global__ __launch_bounds__(256)
void prep_kernel(const int* __restrict__ idx1, const int* __restrict__ batch,
                 int* __restrict__ cnt, int* __restrict__ bcnt, int* __restrict__ elist,
                 const float* __restrict__ emb, float* __restrict__ stats,
                 const float* __restrict__ ln_w, const float* __restrict__ ln_b,
                 const float* __restrict__ W1, float* __restrict__ W1p,
                 float* __restrict__ wbar, float* __restrict__ bbar,
                 int slot, int E, int N, int PB, int SB)
{
    const int b = blockIdx.x;
    if (b < PB) {
        const int i  = b * 256 + threadIdx.x;
        const int i4 = i * 4;
        if (i4 + 3 < E) {
            const int4 v = *(const int4*)&idx1[i4];
            int p;
            p = atomicAdd(&cnt[v.x], 1); if (p < slot) elist[(size_t)v.x * slot + p] = i4;
            p = atomicAdd(&cnt[v.y], 1); if (p < slot) elist[(size_t)v.y * slot + p] = i4 + 1;
            p = atomicAdd(&cnt[v.z], 1); if (p < slot) elist[(size_t)v.z * slot + p] = i4 + 2;
            p = atomicAdd(&cnt[v.w], 1); if (p < slot) elist[(size_t)v.w * slot + p] = i4 + 3;
        } else {
            for (int k2 = i4; k2 < E; ++k2) {
                const int nn = idx1[k2];
                const int p = atomicAdd(&cnt[nn], 1);
                if (p < slot) elist[(size_t)nn * slot + p] = k2;
            }
        }
        if (i < N) atomicAdd(&bcnt[batch[i]], 1);
        return;
    }
    if (b < PB + SB) {
        const int lane = threadIdx.x & 63;
        const int n = (b - PB) * 4 + (threadIdx.x >> 6);
        if (n >= N) return;
        const float* eb = emb + (size_t)n * 1152;
        float er0[9], er1[9];
        #pragma unroll
        for (int l = 0; l < 9; ++l) { er0[l] = eb[l * 128 + lane]; er1[l] = eb[l * 128 + 64 + lane]; }
        float* st = stats + (size_t)n * 56;
        #pragma unroll
        for (int l = 0; l < 9; ++l) {
            const float tot = dpp_sum64(er0[l] + er1[l]);
            if (lane == 63) st[l] = tot;
        }
        int idx = 9;
        #pragma unroll
        for (int l = 0; l < 9; ++l) {
            #pragma unroll
            for (int l2 = l; l2 < 9; ++l2) {
                const float tot = dpp_sum64(er0[l] * er0[l2] + er1[l] * er1[l2]);
                if (lane == 63) st[idx] = tot;
                ++idx;
            }
        }
        return;
    }
    // ---- W1 fold: one block, 256 threads = (k 0..127) x (c-half) ----
    {
        __shared__ float red[2][128][2];
        const int k = threadIdx.x & 127, hf = threadIdx.x >> 7;
        float wb = 0.f, bbv = 0.f;
        const int c0 = hf * 64;
        for (int c = c0; c < c0 + 64; ++c) {
            const float w  = W1[c * 128 + k];
            const float wp = ln_w[c] * w;
            W1p[c * 128 + k] = wp;
            wb  += wp;
            bbv += ln_b[c] * w;
        }
        red[hf][k][0] = wb; red[hf][k][1] = bbv;
        __syncthreads();
        if (hf == 0) {
            wbar[k] = red[0][k][0] + red[1][k][0];
            bbar[k] = red[0][k][1] + red[1][k][1];
        }
    }
}

// main: 4 waves/block, wave = 1 node end-to-end. VGPR<=64 for 8 waves/SIMD.
__global__ __launch_bounds__(256, 8)
void main_kernel(const float* __restrict__ emb, const float* __restrict__ vec,
                 const int* __restrict__ cnt, const int* __restrict__ elist, int slot,
                 const float* __restrict__ sph_w, const float* __restrict__ stats,
                 const float* __restrict__ W1p, const float* __restrict__ wbar,
                 const float* __restrict__ bbar, const float* __restrict__ b1,
                 const float* __restrict__ W2, const float* __restrict__ b2,
                 const int* __restrict__ batch, const int* __restrict__ bcnt,
                 float* __restrict__ out, int N)
{
    __shared__ float S_sh[4][68];   // per-wave: S1[54],S2[6],S3[6] (invc-scaled)

    const int lane = threadIdx.x & 63;
    const int wv   = __builtin_amdgcn_readfirstlane(threadIdx.x >> 6);  // force SGPR
    const int n    = blockIdx.x * 4 + wv;                               // wave-uniform
    if (n >= N) return;

    // ============ phase 1: edges -> S_sh (wave-local, DPP) ============
    {
        const int   cntn = cnt[n];
        const int   cnE  = min(cntn, slot);
        const float invc = 1.f / (float)(cntn > 0 ? cntn : 1);
        const float inv128 = 1.f / 128.f;
        const float* st = stats + (size_t)n * 56;   // SGPR base -> s_load

        float t1[9], mru = 0.f, op[6];
        #pragma unroll
        for (int l = 0; l < 9; ++l) t1[l] = 0.f;
        #pragma unroll
        for (int u = 0; u < 6; ++u) op[u] = 0.f;

        if (lane < cnE) {
            const int e = elist[(size_t)n * slot + lane];
            const float vx = vec[e * 3 + 0];
            const float vy = vec[e * 3 + 1];
            const float vz = vec[e * 3 + 2];
            const float rr = vx * vx + vy * vy + vz * vz;

            const float a1x = SQ3 * vx, a1y = SQ3 * vy, a1z = SQ3 * vz;
            const float q0 = SQ15 * vx * vy;
            const float q1 = SQ15 * vy * vz;
            const float q2 = 0.5f * SQ5 * (3.f * vz * vz - rr);
            const float q3 = SQ15 * vx * vz;
            const float q4 = 0.5f * SQ15 * (vx * vx - vy * vy);
            const float inv1 = sph_w[1] * rsqrtf((a1x*a1x + a1y*a1y + a1z*a1z) * (1.f/3.f) + 1e-6f);
            const float inv2 = sph_w[2] * rsqrtf((q0*q0 + q1*q1 + q2*q2 + q3*q3 + q4*q4) * (1.f/5.f) + 1e-6f);

            float sh[9];
            sh[0] = sph_w[0] * rsqrtf(1.0f + 1e-6f);
            sh[1] = a1x * inv1; sh[2] = a1y * inv1; sh[3] = a1z * inv1;
            sh[4] = q0 * inv2;  sh[5] = q1 * inv2;  sh[6] = q2 * inv2;
            sh[7] = q3 * inv2;  sh[8] = q4 * inv2;

            float mu = 0.f;
            #pragma unroll
            for (int l = 0; l < 9; ++l) mu += sh[l] * st[l];
            mu *= inv128;

            float x2 = 0.f;
            {
                int idx = 9;
                #pragma unroll
                for (int l = 0; l < 9; ++l) {
                    x2 += st[idx] * sh[l] * sh[l]; ++idx;
                    #pragma unroll
                    for (int l2 = l + 1; l2 < 9; ++l2) {
                        x2 += st[idx] * (2.f * sh[l] * sh[l2]); ++idx;
                    }
                }
            }
            x2 *= inv128;

            const float rinv = rsqrtf(x2 - mu * mu + 1e-5f);
            #pragma unroll
            for (int l = 0; l < 9; ++l) t1[l] = rinv * sh[l];
            mru = rinv * mu;
            op[0] = vx*vx; op[1] = vx*vy; op[2] = vx*vz;
            op[3] = vy*vy; op[4] = vy*vz; op[5] = vz*vz;
        }

        #pragma unroll
        for (int u = 0; u < 6; ++u) {
            #pragma unroll
            for (int l = 0; l < 9; ++l) {
                const float tot = dpp_sum64(op[u] * t1[l]);
                if (lane == 63) S_sh[wv][u * 9 + l] = tot * invc;
            }
        }
        #pragma unroll
        for (int u = 0; u < 6; ++u) {
            const float tot = dpp_sum64(op[u] * mru);
            if (lane == 63) S_sh[wv][54 + u] = tot * invc;
        }
        #pragma unroll
        for (int u = 0; u < 6; ++u) {
            const float tot = dpp_sum64(op[u]);
            if (lane == 63) S_sh[wv][60 + u] = tot * invc;
        }
    }
    wave_fence();

    // ============ phase 2: G[l][k2] = emb_n (9x128) x W1p (128x128) ==========
    // emb rows: SGPR s_load_dwordx8 (SMEM pipe); W1p: coalesced float2 (VMEM).
    const int k2 = 2 * lane;
    const float* eb = emb + (size_t)n * 1152;   // SGPR base

    float2 g[9];
    #pragma unroll
    for (int l = 0; l < 9; ++l) g[l] = make_float2(0.f, 0.f);

    const float* wp = W1p + k2;
    for (int c0 = 0; c0 < 128; c0 += 8) {
        float2 w8[8];
        #pragma unroll
        for (int cc = 0; cc < 8; ++cc)
            w8[cc] = *(const float2*)(wp + (size_t)(c0 + cc) * 128);
        #pragma unroll
        for (int l = 0; l < 9; ++l) {
            const float* r = eb + l * 128 + c0;   // uniform -> s_load_dwordx8
            #pragma unroll
            for (int cc = 0; cc < 8; ++cc) {
                const float e = r[cc];
                g[l].x = fmaf(e, w8[cc].x, g[l].x);
                g[l].y = fmaf(e, w8[cc].y, g[l].y);
            }
        }
    }

    // ============ phase 3: z = S1*G - S2*wbar + S3*bbar + b1; silu; W2 ======
    {
        const float2 wbv = *(const float2*)(wbar + k2);
        const float2 bbv = *(const float2*)(bbar + k2);
        const float2 b1v = *(const float2*)(b1 + k2);
        const float2 w2v = *(const float2*)(W2 + k2);

        const float* Sp = &S_sh[wv][0];
        float sv[6];
        #pragma unroll
        for (int u = 0; u < 6; ++u) {
            float zx = b1v.x, zy = b1v.y;
            #pragma unroll
            for (int l = 0; l < 9; ++l) {
                const float s1 = Sp[u * 9 + l];
                zx = fmaf(s1, g[l].x, zx);
                zy = fmaf(s1, g[l].y, zy);
            }
            const float S2u = Sp[54 + u], S3u = Sp[60 + u];
            zx = fmaf(-S2u, wbv.x, fmaf(S3u, bbv.x, zx));
            zy = fmaf(-S2u, wbv.y, fmaf(S3u, bbv.y, zy));
            const float gx = zx / (1.f + __expf(-zx));
            const float gy = zy / (1.f + __expf(-zy));
            sv[u] = dpp_sum64(fmaf(gx, w2v.x, gy * w2v.y));
        }

        if (lane == 63) {
            const float bb2 = b2[0];
            const int bidx = batch[n];
            const int cb = bcnt[bidx];
            const float ic = 1.f / (float)(cb > 0 ? cb : 1);
            const int base = bidx * 9;
            const float o0 = (sv[0] + bb2) * ic;
            const float o1 = (sv[1] + bb2) * ic;
            const float o2 = (sv[2] + bb2) * ic;
            const float o3 = (sv[3] + bb2) * ic;
            const float o4 = (sv[4] + bb2) * ic;
            const float o5 = (sv[5] + bb2) * ic;
            atomicAdd(&out[base + 0], o0);
            atomicAdd(&out[base + 1], o1);
            atomicAdd(&out[base + 2], o2);
            atomicAdd(&out[base + 3], o1);
            atomicAdd(&out[base + 4], o3);
            atomicAdd(&out[base + 5], o4);
            atomicAdd(&out[base + 6], o2);
            atomicAdd(&out[base + 7], o4);
            atomicAdd(&out[base + 8], o5);
        }
    }
}

extern "C" void kernel_launch(void* const* d_in, const int* in_sizes, int n_in,
                              void* d_out, int out_size, void* d_ws, size_t ws_size,
                              hipStream_t stream) {
    const float* emb   = (const float*)d_in[0];
    const float* vec   = (const float*)d_in[1];
    const int*   eidx  = (const int*)  d_in[2];
    const int*   batch = (const int*)  d_in[3];
    const float* sph_w = (const float*)d_in[4];
    const float* ln_w  = (const float*)d_in[5];
    const float* ln_b  = (const float*)d_in[6];
    const float* W1    = (const float*)d_in[7];
    const float* b1    = (const float*)d_in[8];
    const float* W2    = (const float*)d_in[9];
    const float* b2    = (const float*)d_in[10];

    const int N = in_sizes[3];
    const int E = in_sizes[1] / 3;
    const int B = out_size / 9;
    const int* idx1 = eidx + E;   // edge_index[1]

    // ws: [cnt N][bcnt B][elist N*slot][stats N*56][W1p 16384][wbar 128][bbar 128]
    int slot = 64;
    {
        const size_t base = (size_t)(N + B) + (size_t)N * 56 + 16384 + 256;
        while (slot > 1 && (base + (size_t)N * slot) * 4 > ws_size) slot >>= 1;
    }
    int*   cnt   = (int*)d_ws;
    int*   bcnt  = cnt + N;
    int*   elist = bcnt + B;
    float* stats = (float*)(elist + (size_t)N * slot);
    float* W1p   = stats + (size_t)N * 56;
    float* wbar  = W1p + 16384;
    float* bbar  = wbar + 128;

    hipMemsetAsync(d_out, 0, (size_t)out_size * sizeof(float), stream);
    hipMemsetAsync(cnt, 0, (size_t)(N + B) * sizeof(int), stream);

    const int PB = (max((E + 3) / 4, N) + 255) / 256;
    const int SB = (N + 3) / 4;
    prep_kernel<<<PB + SB + 1, 256, 0, stream>>>(idx1, batch, cnt, bcnt, elist,
                                                 emb, stats, ln_w, ln_b, W1,
                                                 W1p, wbar, bbar, slot, E, N, PB, SB);
    main_kernel<<<(N + 3) / 4, 256, 0, stream>>>(
        emb, vec, cnt, elist, slot, sph_w, stats, W1p, wbar, bbar,
        b1, W2, b2, batch, bcnt, (float*)d_out, N);
}

// Round 11
// 182.495 us; speedup vs baseline: 1.3147x; 1.0371x over previous
//
#include <hip/hip_runtime.h>

// Rank2SymmetricTensorHead — bucket + fused(stats|edges|contraction|GEMM).
// Algebra (absmax 0.0 since round 3): layernorm is affine per edge =>
//   no[c][u] = invc*( lw_c*(emb[.,c].S1[u] - S2[u]) + lb_c*S3[u] )
// per-node S1[6][9],S2[6],S3[6]; per-edge mu/var from per-node mbar[9]+Gram[45].
// z[u,k] = sum_c no[c][u]*W1[c,k] + b1[k]; out = silu(z)·W2 + b2, batch-mean.
//
// fused: wave owns 2 nodes; per node (wave-local, no __syncthreads):
//   P0 stats: er regs (coalesced) -> 54 DPP chains -> statsL
//   P1 edges: lane/edge -> 66 DPP chains -> S_sh (invc-scaled)
//   P2 contraction: er regs + S_sh -> A2[s][u][c] (b32 writes, conflict-free)
//   P3 GEMM: half-wave = node, lane owns 4 k's; per 4-c step:
//       6 uniform ds_read_b128 (2-way=free) + 4x512B W1 loads + 96 FMA
//       -> VALU-bound (192 cyc VALU vs ~144 DS-pipe per CU)
//   P4 silu·W2, half-wave DPP reduce, atomicAdd(out/bcnt)

#define SQ3  1.73205080756887729f
#define SQ15 3.87298334620741688f
#define SQ5  2.23606797749978970f

__device__ __forceinline__ float dpp_sum64(float v) {
    // 64-lane sum, result valid in lane 63. Pure VALU.
    int x;
    x = __builtin_amdgcn_update_dpp(0, __float_as_int(v), 0x111, 0xF, 0xF, true); v += __int_as_float(x);
    x = __builtin_amdgcn_update_dpp(0, __float_as_int(v), 0x112, 0xF, 0xF, true); v += __int_as_float(x);
    x = __builtin_amdgcn_update_dpp(0, __float_as_int(v), 0x114, 0xF, 0xF, true); v += __int_as_float(x);
    x = __builtin_amdgcn_update_dpp(0, __float_as_int(v), 0x118, 0xF, 0xF, true); v += __int_as_float(x);
    x = __builtin_amdgcn_update_dpp(0, __float_as_int(v), 0x142, 0xA, 0xF, true); v += __int_as_float(x);
    x = __builtin_amdgcn_update_dpp(0, __float_as_int(v), 0x143, 0xC, 0xF, true); v += __int_as_float(x);
    return v;
}

__device__ __forceinline__ float dpp_sum32(float v) {
    // per-32-lane-half sums: lane31 = sum(0..31), lane63 = sum(32..63).
    int x;
    x = __builtin_amdgcn_update_dpp(0, __float_as_int(v), 0x111, 0xF, 0xF, true); v += __int_as_float(x);
    x = __builtin_amdgcn_update_dpp(0, __float_as_int(v), 0x112, 0xF, 0xF, true); v += __int_as_float(x);
    x = __builtin_amdgcn_update_dpp(0, __float_as_int(v), 0x114, 0xF, 0xF, true); v += __int_as_float(x);
    x = __builtin_amdgcn_update_dpp(0, __float_as_int(v), 0x118, 0xF, 0xF, true); v += __int_as_float(x);
    x = __builtin_amdgcn_update_dpp(0, __float_as_int(v), 0x142, 0xA, 0xF, true); v += __int_as_float(x);
    return v;
}

__device__ __forceinline__ void wave_fence() {
    __builtin_amdgcn_wave_barrier();
    asm volatile("" ::: "memory");
}

__global__ __launch_bounds__(256)
void bucket_kernel(const int* __restrict__ idx1, const int* __restrict__ batch,
                   int* __restrict__ cnt, int* __restrict__ bcnt,
                   int* __restrict__ elist, int slot, int E, int N) {
    const int i  = blockIdx.x * 256 + threadIdx.x;
    const int i4 = i * 4;
    if (i4 + 3 < E) {
        const int4 v = *(const int4*)&idx1[i4];
        int p;
        p = atomicAdd(&cnt[v.x], 1); if (p < slot) elist[(size_t)v.x * slot + p] = i4;
        p = atomicAdd(&cnt[v.y], 1); if (p < slot) elist[(size_t)v.y * slot + p] = i4 + 1;
        p = atomicAdd(&cnt[v.z], 1); if (p < slot) elist[(size_t)v.z * slot + p] = i4 + 2;
        p = atomicAdd(&cnt[v.w], 1); if (p < slot) elist[(size_t)v.w * slot + p] = i4 + 3;
    } else {
        for (int k2 = i4; k2 < E; ++k2) {
            const int nn = idx1[k2];
            const int p = atomicAdd(&cnt[nn], 1);
            if (p < slot) elist[(size_t)nn * slot + p] = k2;
        }
    }
    if (i < N) atomicAdd(&bcnt[batch[i]], 1);
}

__global__ __launch_bounds__(256, 4)
void fused_kernel(const float* __restrict__ emb, const float* __restrict__ vec,
                  const int* __restrict__ cnt, const int* __restrict__ elist, int slot,
                  const float* __restrict__ sph_w,
                  const float* __restrict__ ln_w, const float* __restrict__ ln_b,
                  const float* __restrict__ W1, const float* __restrict__ b1,
                  const float* __restrict__ W2, const float* __restrict__ b2,
                  const int* __restrict__ batch, const int* __restrict__ bcnt,
                  float* __restrict__ out, int N)
{
    __shared__ float statsL[4][56];      // per-wave scratch: mbar[9], Gram[45]
    __shared__ float S_sh[4][2][68];     // per-wave,node: S1[54],S2[6],S3[6]
    __shared__ float A2[4][2][6][128];   // per-wave,node: no^T[u][c]  (24 KB)

    const int lane = threadIdx.x & 63;
    const int wv   = __builtin_amdgcn_readfirstlane(threadIdx.x >> 6);
    const int n0   = (blockIdx.x * 4 + wv) * 2;
    if (n0 >= N) return;

    const float lw0 = ln_w[lane], lb0 = ln_b[lane];
    const float lw1 = ln_w[lane + 64], lb1 = ln_b[lane + 64];
    const float spw0 = sph_w[0], spw1 = sph_w[1], spw2 = sph_w[2];

    #pragma unroll
    for (int s = 0; s < 2; ++s) {
        const int n = n0 + s;
        if (n >= N) break;
        const float* eb = emb + (size_t)n * 1152;

        // ---- P0: load emb (coalesced), stats -> statsL ----
        float er0[9], er1[9];
        #pragma unroll
        for (int l = 0; l < 9; ++l) { er0[l] = eb[l * 128 + lane]; er1[l] = eb[l * 128 + 64 + lane]; }
        #pragma unroll
        for (int l = 0; l < 9; ++l) {
            const float tot = dpp_sum64(er0[l] + er1[l]);
            if (lane == 63) statsL[wv][l] = tot;
        }
        {
            int idx = 9;
            #pragma unroll
            for (int l = 0; l < 9; ++l) {
                #pragma unroll
                for (int l2 = l; l2 < 9; ++l2) {
                    const float tot = dpp_sum64(er0[l] * er0[l2] + er1[l] * er1[l2]);
                    if (lane == 63) statsL[wv][idx] = tot;
                    ++idx;
                }
            }
        }
        wave_fence();

        // ---- P1: edges -> S_sh[wv][s] ----
        {
            const int   cntn = cnt[n];
            const int   cnE  = min(cntn, slot);
            const float invc = 1.f / (float)(cntn > 0 ? cntn : 1);
            const float inv128 = 1.f / 128.f;
            const float* st = &statsL[wv][0];

            float t1[9], mru = 0.f, op[6];
            #pragma unroll
            for (int l = 0; l < 9; ++l) t1[l] = 0.f;
            #pragma unroll
            for (int u = 0; u < 6; ++u) op[u] = 0.f;

            if (lane < cnE) {
                const int e = elist[(size_t)n * slot + lane];
                const float vx = vec[e * 3 + 0];
                const float vy = vec[e * 3 + 1];
                const float vz = vec[e * 3 + 2];
                const float rr = vx * vx + vy * vy + vz * vz;

                const float a1x = SQ3 * vx, a1y = SQ3 * vy, a1z = SQ3 * vz;
                const float q0 = SQ15 * vx * vy;
                const float q1 = SQ15 * vy * vz;
                const float q2 = 0.5f * SQ5 * (3.f * vz * vz - rr);
                const float q3 = SQ15 * vx * vz;
                const float q4 = 0.5f * SQ15 * (vx * vx - vy * vy);
                const float inv1 = spw1 * rsqrtf((a1x*a1x + a1y*a1y + a1z*a1z) * (1.f/3.f) + 1e-6f);
                const float inv2 = spw2 * rsqrtf((q0*q0 + q1*q1 + q2*q2 + q3*q3 + q4*q4) * (1.f/5.f) + 1e-6f);

                float sh[9];
                sh[0] = spw0 * rsqrtf(1.0f + 1e-6f);
                sh[1] = a1x * inv1; sh[2] = a1y * inv1; sh[3] = a1z * inv1;
                sh[4] = q0 * inv2;  sh[5] = q1 * inv2;  sh[6] = q2 * inv2;
                sh[7] = q3 * inv2;  sh[8] = q4 * inv2;

                float mu = 0.f;
                #pragma unroll
                for (int l = 0; l < 9; ++l) mu += sh[l] * st[l];
                mu *= inv128;

                float x2 = 0.f;
                {
                    int idx = 9;
                    #pragma unroll
                    for (int l = 0; l < 9; ++l) {
                        x2 += st[idx] * sh[l] * sh[l]; ++idx;
                        #pragma unroll
                        for (int l2 = l + 1; l2 < 9; ++l2) {
                            x2 += st[idx] * (2.f * sh[l] * sh[l2]); ++idx;
                        }
                    }
                }
                x2 *= inv128;

                const float rinv = rsqrtf(x2 - mu * mu + 1e-5f);
                #pragma unroll
                for (int l = 0; l < 9; ++l) t1[l] = rinv * sh[l];
                mru = rinv * mu;
                op[0] = vx*vx; op[1] = vx*vy; op[2] = vx*vz;
                op[3] = vy*vy; op[4] = vy*vz; op[5] = vz*vz;
            }

            #pragma unroll
            for (int u = 0; u < 6; ++u) {
                #pragma unroll
                for (int l = 0; l < 9; ++l) {
                    const float tot = dpp_sum64(op[u] * t1[l]);
                    if (lane == 63) S_sh[wv][s][u * 9 + l] = tot * invc;
                }
            }
            #pragma unroll
            for (int u = 0; u < 6; ++u) {
                const float tot = dpp_sum64(op[u] * mru);
                if (lane == 63) S_sh[wv][s][54 + u] = tot * invc;
            }
            #pragma unroll
            for (int u = 0; u < 6; ++u) {
                const float tot = dpp_sum64(op[u]);
                if (lane == 63) S_sh[wv][s][60 + u] = tot * invc;
            }
        }
        wave_fence();

        // ---- P2: contraction -> A2[wv][s][u][c] (conflict-free b32 writes) ----
        {
            const float* Sp = &S_sh[wv][s][0];
            #pragma unroll
            for (int u = 0; u < 6; ++u) {
                float a0 = 0.f, a1 = 0.f;
                #pragma unroll
                for (int l = 0; l < 9; ++l) {
                    const float s1 = Sp[u * 9 + l];
                    a0 = fmaf(er0[l], s1, a0);
                    a1 = fmaf(er1[l], s1, a1);
                }
                const float S2u = Sp[54 + u], S3u = Sp[60 + u];
                A2[wv][s][u][lane]      = fmaf(lw0, a0 - S2u, lb0 * S3u);
                A2[wv][s][u][lane + 64] = fmaf(lw1, a1 - S2u, lb1 * S3u);
            }
        }
        wave_fence();
    }

    // ---- P3: GEMM — half-wave = node, lane owns 4 k's ----
    const int h  = lane >> 5;          // node within pair
    const int k4 = (lane & 31) * 4;    // k columns

    float4 acc[6];
    #pragma unroll
    for (int u = 0; u < 6; ++u) acc[u] = make_float4(0.f, 0.f, 0.f, 0.f);

    const float* w1base = W1 + k4;
    for (int c4 = 0; c4 < 128; c4 += 4) {
        float4 a[6];
        #pragma unroll
        for (int u = 0; u < 6; ++u) a[u] = *(const float4*)&A2[wv][h][u][c4];
        float4 w[4];
        #pragma unroll
        for (int cc = 0; cc < 4; ++cc)
            w[cc] = *(const float4*)(w1base + (size_t)(c4 + cc) * 128);
        #pragma unroll
        for (int cc = 0; cc < 4; ++cc) {
            #pragma unroll
            for (int u = 0; u < 6; ++u) {
                const float sa = ((const float*)&a[u])[cc];
                acc[u].x = fmaf(sa, w[cc].x, acc[u].x);
                acc[u].y = fmaf(sa, w[cc].y, acc[u].y);
                acc[u].z = fmaf(sa, w[cc].z, acc[u].z);
                acc[u].w = fmaf(sa, w[cc].w, acc[u].w);
            }
        }
    }

    // ---- P4: silu · W2, half-wave reduce, atomic out ----
    {
        const float4 b1v = *(const float4*)&b1[k4];
        const float4 w2v = *(const float4*)&W2[k4];
        float sv[6];
        #pragma unroll
        for (int u = 0; u < 6; ++u) {
            const float zx = acc[u].x + b1v.x;
            const float zy = acc[u].y + b1v.y;
            const float zz = acc[u].z + b1v.z;
            const float zw = acc[u].w + b1v.w;
            const float gx = zx / (1.f + __expf(-zx));
            const float gy = zy / (1.f + __expf(-zy));
            const float gz = zz / (1.f + __expf(-zz));
            const float gw = zw / (1.f + __expf(-zw));
            const float sdot = fmaf(gx, w2v.x, fmaf(gy, w2v.y, fmaf(gz, w2v.z, gw * w2v.w)));
            sv[u] = dpp_sum32(sdot);
        }

        if ((lane & 31) == 31) {
            const int n = n0 + (lane >> 5);
            if (n < N) {
                const float bb2 = b2[0];
                const int bidx = batch[n];
                const int cb = bcnt[bidx];
                const float ic = 1.f / (float)(cb > 0 ? cb : 1);
                const int base = bidx * 9;
                const float o0 = (sv[0] + bb2) * ic;
                const float o1 = (sv[1] + bb2) * ic;
                const float o2 = (sv[2] + bb2) * ic;
                const float o3 = (sv[3] + bb2) * ic;
                const float o4 = (sv[4] + bb2) * ic;
                const float o5 = (sv[5] + bb2) * ic;
                atomicAdd(&out[base + 0], o0);
                atomicAdd(&out[base + 1], o1);
                atomicAdd(&out[base + 2], o2);
                atomicAdd(&out[base + 3], o1);
                atomicAdd(&out[base + 4], o3);
                atomicAdd(&out[base + 5], o4);
                atomicAdd(&out[base + 6], o2);
                atomicAdd(&out[base + 7], o4);
                atomicAdd(&out[base + 8], o5);
            }
        }
    }
}

extern "C" void kernel_launch(void* const* d_in, const int* in_sizes, int n_in,
                              void* d_out, int out_size, void* d_ws, size_t ws_size,
                              hipStream_t stream) {
    const float* emb   = (const float*)d_in[0];
    const float* vec   = (const float*)d_in[1];
    const int*   eidx  = (const int*)  d_in[2];
    const int*   batch = (const int*)  d_in[3];
    const float* sph_w = (const float*)d_in[4];
    const float* ln_w  = (const float*)d_in[5];
    const float* ln_b  = (const float*)d_in[6];
    const float* W1    = (const float*)d_in[7];
    const float* b1    = (const float*)d_in[8];
    const float* W2    = (const float*)d_in[9];
    const float* b2    = (const float*)d_in[10];

    const int N = in_sizes[3];
    const int E = in_sizes[1] / 3;
    const int B = out_size / 9;
    const int* idx1 = eidx + E;   // edge_index[1]

    // ws: [cnt N][bcnt B][elist N*slot]
    int slot = 64;
    {
        const size_t base = (size_t)(N + B);
        while (slot > 1 && (base + (size_t)N * slot) * 4 > ws_size) slot >>= 1;
    }
    int* cnt   = (int*)d_ws;
    int* bcnt  = cnt + N;
    int* elist = bcnt + B;

    hipMemsetAsync(d_out, 0, (size_t)out_size * sizeof(float), stream);
    hipMemsetAsync(cnt, 0, (size_t)(N + B) * sizeof(int), stream);

    const int pwork = max((E + 3) / 4, N);
    bucket_kernel<<<(pwork + 255) / 256, 256, 0, stream>>>(idx1, batch, cnt, bcnt,
                                                           elist, slot, E, N);
    fused_kernel<<<(N + 7) / 8, 256, 0, stream>>>(
        emb, vec, cnt, elist, slot, sph_w, ln_w, ln_b,
        W1, b1, W2, b2, batch, bcnt, (float*)d_out, N);
}